// Round 1
// baseline (469.914 us; speedup 1.0000x reference)
//
#include <hip/hip_runtime.h>

// SparseConv2d == dense 3x3 conv, stride 1, pad 1, NCHW/OIHW, fp32.
// N=16, Cin=32, Cout=32, H=W=256.
//
// R1 baseline: fp32 direct conv.
//  - block = 256 threads = one (n, h) output row, all 32 oc, all 256 w
//  - thread = 4(w) x 8(oc) micro-tile -> 32 accumulators, 9216 FMAs/thread
//  - weights transposed [ic][kh][kw][oc] in LDS (36 KB), float4 broadcast reads
//  - input: one coalesced float4 per (ic,kh), halo via wave shuffles
// Predicted: ~150-190 us, VALUBusy-bound (no fp32 MFMA on CDNA4).

constexpr int N_  = 16;
constexpr int C_  = 32;   // in channels
constexpr int OC_ = 32;   // out channels
constexpr int H_  = 256;
constexpr int W_  = 256;

__global__ __launch_bounds__(256) void conv3x3_fp32_kernel(
    const float* __restrict__ x,     // [N][C][H][W]
    const float* __restrict__ wgt,   // [OC][C][3][3]
    const float* __restrict__ bias,  // [OC]
    float* __restrict__ out)         // [N][OC][H][W]
{
    __shared__ __align__(16) float ldsW[C_ * 9 * OC_];  // [ic][kh][kw][oc]

    const int tid = threadIdx.x;

    // Stage weights transposed: ldsW[((ic*3+kh)*3+kw)*32 + oc]
    for (int i = tid; i < C_ * 9 * OC_; i += 256) {
        const int oc  = i & 31;
        const int r   = i >> 5;        // ic*9 + kh*3 + kw
        const int ic  = r / 9;
        const int rem = r % 9;         // kh*3 + kw
        ldsW[i] = wgt[(oc * C_ + ic) * 9 + rem];
    }
    __syncthreads();

    const int bx   = blockIdx.x;
    const int n    = bx >> 8;          // / H_
    const int h    = bx & (H_ - 1);
    const int lane = tid & 63;         // w-column (wave = 64 consecutive cols)
    const int ocg  = tid >> 6;         // 0..3
    const int oc0  = ocg * 8;
    const int w0   = lane * 4;

    float acc[8][4];
    #pragma unroll
    for (int o = 0; o < 8; ++o) {
        const float b = bias[oc0 + o];
        #pragma unroll
        for (int j = 0; j < 4; ++j) acc[o][j] = b;
    }

    for (int ic = 0; ic < C_; ++ic) {
        const float* xplane = x + ((size_t)(n * C_ + ic) * H_) * W_;
        #pragma unroll
        for (int kh = 0; kh < 3; ++kh) {
            const int hy = h + kh - 1;
            if (hy < 0 || hy >= H_) continue;   // wave-uniform (h is block-uniform)
            const float* row = xplane + (size_t)hy * W_;

            // Coalesced 16B load + halo from neighbor lanes.
            const float4 f4 = *(const float4*)(row + w0);
            float xm1 = __shfl_up(f4.w, 1);
            float xp4 = __shfl_down(f4.x, 1);
            if (lane == 0)  xm1 = 0.0f;   // w = -1 pad
            if (lane == 63) xp4 = 0.0f;   // w = 256 pad
            const float xv[6] = {xm1, f4.x, f4.y, f4.z, f4.w, xp4};

            const float* wbase = &ldsW[(ic * 9 + kh * 3) * 32 + oc0];
            #pragma unroll
            for (int kw = 0; kw < 3; ++kw) {
                const float4 wa = *(const float4*)(wbase + kw * 32);
                const float4 wb = *(const float4*)(wbase + kw * 32 + 4);
                #pragma unroll
                for (int j = 0; j < 4; ++j) {
                    const float xj = xv[j + kw];
                    acc[0][j] += xj * wa.x;
                    acc[1][j] += xj * wa.y;
                    acc[2][j] += xj * wa.z;
                    acc[3][j] += xj * wa.w;
                    acc[4][j] += xj * wb.x;
                    acc[5][j] += xj * wb.y;
                    acc[6][j] += xj * wb.z;
                    acc[7][j] += xj * wb.w;
                }
            }
        }
    }

    #pragma unroll
    for (int o = 0; o < 8; ++o) {
        float4 v = make_float4(acc[o][0], acc[o][1], acc[o][2], acc[o][3]);
        *(float4*)(out + (((size_t)(n * OC_ + oc0 + o) * H_) + h) * W_ + w0) = v;
    }
}

extern "C" void kernel_launch(void* const* d_in, const int* in_sizes, int n_in,
                              void* d_out, int out_size, void* d_ws, size_t ws_size,
                              hipStream_t stream) {
    const float* x    = (const float*)d_in[0];
    const float* wgt  = (const float*)d_in[1];
    const float* bias = (const float*)d_in[2];
    float* out        = (float*)d_out;

    dim3 grid(N_ * H_);   // 4096 blocks: one per (n, h)
    dim3 block(256);
    conv3x3_fp32_kernel<<<grid, block, 0, stream>>>(x, wgt, bias, out);
}

// Round 2
// 269.185 us; speedup vs baseline: 1.7457x; 1.7457x over previous
//
#include <hip/hip_runtime.h>

// 3x3 conv, stride 1, pad 1, NCHW/OIHW fp32. N=16, C=32, OC=32, H=W=256.
//
// R2: bf16 MFMA implicit GEMM, single pass.
//  - block = 256 thr (4 waves) = one (n, h) output row, all 32 oc, 256 w
//  - LDS: x rows h-1,h,h+1 transposed to bf16 [wi][ic], w-stride 80B
//    (b128 frag reads + packed b32 transpose writes ~conflict-free);
//    weights bf16 [kh*3+kw][oc][ic] (A-frags read once per block)
//  - mfma_f32_32x32x16_bf16: D[oc, w], K = ic-half(16) x 2 x 9 taps = 288
//  - wave = 2 w-tiles of 32 -> 2 x 16 acc VGPRs; bias in acc init
//  - XCD swizzle: consecutive h rows on same XCD -> L2 absorbs 3x row re-read
// Predicted: 60-85 us, memory-bound (~300 MB HBM traffic).

constexpr int N_  = 16;
constexpr int C_  = 32;
constexpr int OC_ = 32;
constexpr int H_  = 256;
constexpr int W_  = 256;

constexpr int WSTR = 40;            // ushorts per w entry (80 B: 64 data + 16 pad)
constexpr int RSTR = 258 * WSTR;    // ushorts per staged row (wi = w+1, 0..257)

typedef __attribute__((ext_vector_type(8)))  short short8;
typedef __attribute__((ext_vector_type(16))) float float16;

static __device__ __forceinline__ unsigned short f2bf(float f) {
    unsigned int u = __float_as_uint(f);
    unsigned int r = (u + 0x7FFFu + ((u >> 16) & 1u)) >> 16;   // RNE
    return (unsigned short)r;
}

__global__ __launch_bounds__(256, 2) void conv3x3_mfma_kernel(
    const float* __restrict__ x,     // [N][C][H][W]
    const float* __restrict__ wgt,   // [OC][C][3][3]
    const float* __restrict__ bias,  // [OC]
    float* __restrict__ out)         // [N][OC][H][W]
{
    __shared__ __align__(16) unsigned short ldsX[3 * RSTR];      // 61,920 B
    __shared__ __align__(16) unsigned short ldsW[9 * 32 * 32];   // 18,432 B

    const int tid = threadIdx.x;

    // XCD-aware swizzle: 8 XCDs x 512 consecutive (n,h) rows each.
    const int id = blockIdx.x;
    const int L  = (id & 7) * 512 + (id >> 3);
    const int n  = L >> 8;
    const int h  = L & (H_ - 1);

    // ---- stage weights: [k9][oc][ic] bf16 ----
    for (int i = tid; i < OC_ * C_ * 9; i += 256) {
        const float v = wgt[i];
        const int oc  = i / 288;
        const int rem = i - oc * 288;
        const int ic  = rem / 9;
        const int k9  = rem - ic * 9;
        ldsW[(k9 * 32 + oc) * 32 + ic] = f2bf(v);
    }

    // ---- stage x rows h-1,h,h+1 transposed to bf16 [wi][ic] ----
    const int wlo = tid & 15;        // w low bits (lanes: consecutive w)
    const int ic2 = tid >> 4;        // ic pair 0..15
    #pragma unroll
    for (int r = 0; r < 3; ++r) {
        const int hy = h + r - 1;                    // block-uniform branch
        unsigned short* dst = &ldsX[r * RSTR];
        if (hy >= 0 && hy < H_) {
            const float* p0 = x + (((size_t)(n * C_ + 2 * ic2) * H_ + hy) * W_);
            const float* p1 = p0 + (size_t)H_ * W_;  // next ic plane
            #pragma unroll
            for (int wb = 0; wb < 16; ++wb) {
                const int w = wb * 16 + wlo;
                const unsigned int u =
                    (unsigned int)f2bf(p0[w]) | ((unsigned int)f2bf(p1[w]) << 16);
                *(unsigned int*)&dst[(w + 1) * WSTR + 2 * ic2] = u;
            }
        } else {
            #pragma unroll
            for (int wb = 0; wb < 16; ++wb) {
                const int w = wb * 16 + wlo;
                *(unsigned int*)&dst[(w + 1) * WSTR + 2 * ic2] = 0u;
            }
        }
    }
    // halo columns w=-1 (wi=0) and w=256 (wi=257) -> zero
    if (tid < 96) {
        const int r  = tid >> 5;
        const int q  = tid & 31;
        const int wi = (q & 16) ? 257 : 0;
        *(unsigned int*)&ldsX[r * RSTR + wi * WSTR + (q & 15) * 2] = 0u;
    }
    __syncthreads();

    // ---- MFMA main loop ----
    const int lane = tid & 63;
    const int wv   = tid >> 6;       // wave 0..3
    const int col  = lane & 31;      // A: oc row; B: w col; D: w col
    const int qd   = lane >> 5;      // k-quad select

    float16 acc0, acc1;
    #pragma unroll
    for (int r = 0; r < 16; ++r) {
        const float bv = bias[(r & 3) + 8 * (r >> 2) + 4 * qd];
        acc0[r] = bv;
        acc1[r] = bv;
    }

    const int w0a = wv * 64;
    const int w0b = wv * 64 + 32;

    #pragma unroll
    for (int kh = 0; kh < 3; ++kh) {
        #pragma unroll
        for (int kw = 0; kw < 3; ++kw) {
            const int t9 = kh * 3 + kw;
            #pragma unroll
            for (int ih = 0; ih < 2; ++ih) {
                const short8 av =
                    *(const short8*)&ldsW[(t9 * 32 + col) * 32 + ih * 16 + qd * 8];
                const short8 b0 =
                    *(const short8*)&ldsX[kh * RSTR + (w0a + col + kw) * WSTR + ih * 16 + qd * 8];
                const short8 b1 =
                    *(const short8*)&ldsX[kh * RSTR + (w0b + col + kw) * WSTR + ih * 16 + qd * 8];
                acc0 = __builtin_amdgcn_mfma_f32_32x32x16_bf16(av, b0, acc0, 0, 0, 0);
                acc1 = __builtin_amdgcn_mfma_f32_32x32x16_bf16(av, b1, acc1, 0, 0, 0);
            }
        }
    }

    // ---- epilogue: D row = oc, col = w ----
    float* outp = out + (size_t)n * OC_ * H_ * W_ + (size_t)h * W_;
    #pragma unroll
    for (int r = 0; r < 16; ++r) {
        const int oc = (r & 3) + 8 * (r >> 2) + 4 * qd;
        outp[(size_t)oc * H_ * W_ + w0a + col] = acc0[r];
        outp[(size_t)oc * H_ * W_ + w0b + col] = acc1[r];
    }
}

extern "C" void kernel_launch(void* const* d_in, const int* in_sizes, int n_in,
                              void* d_out, int out_size, void* d_ws, size_t ws_size,
                              hipStream_t stream) {
    const float* x    = (const float*)d_in[0];
    const float* wgt  = (const float*)d_in[1];
    const float* bias = (const float*)d_in[2];
    float* out        = (float*)d_out;

    dim3 grid(N_ * H_);   // 4096 blocks: one per (n, h)
    dim3 block(256);
    conv3x3_mfma_kernel<<<grid, block, 0, stream>>>(x, wgt, bias, out);
}

// Round 3
// 262.328 us; speedup vs baseline: 1.7913x; 1.0261x over previous
//
#include <hip/hip_runtime.h>

// 3x3 conv, stride 1, pad 1, NCHW/OIHW fp32. N=16, C=32, OC=32, H=W=256.
//
// R3: bf16 MFMA implicit GEMM, bank-conflict-free LDS + 3 blocks/CU.
//  - block = 256 thr (4 waves) = one (n, h) row; wave = 2 w-tiles of 32
//  - ic-half split: stage 16 ic at a time -> ldsX 31KB + ldsW 20.7KB = 51.7KB
//    -> 3 blocks/CU (12 waves), was 2 (8 waves)
//  - ldsX stride 20 ushorts (10 dw, gcd(10,32)=2 -> 2-way = free) for B-frags
//  - ldsW stride 36 ushorts (18 dw, gcd(18,32)=2 -> 2-way) for A-frags
//    (R2 had 16 dw stride = 16-way conflict = the 1.46e7 conflict cycles)
//  - all LDS frag reads are 8B-aligned ds_read_b64 pairs (b128 would misalign)
// Predicted: 60-75 us, conflicts <3e6, occupancy ~35%.

constexpr int N_  = 16;
constexpr int C_  = 32;
constexpr int OC_ = 32;
constexpr int H_  = 256;
constexpr int W_  = 256;

constexpr int XSTR = 20;             // ushorts per wi: 32B data (16 ic) + 8B pad
constexpr int XROW = 258 * XSTR;     // ushorts per staged row (wi = w+1)
constexpr int WSTRD = 36;            // ushorts per (t9,oc): 64B data + 8B pad

typedef __attribute__((ext_vector_type(4)))  short short4v;
typedef __attribute__((ext_vector_type(8)))  short short8v;
typedef __attribute__((ext_vector_type(16))) float float16v;

static __device__ __forceinline__ unsigned short f2bf(float f) {
    unsigned int u = __float_as_uint(f);
    unsigned int r = (u + 0x7FFFu + ((u >> 16) & 1u)) >> 16;   // RNE
    return (unsigned short)r;
}

static __device__ __forceinline__ unsigned pk2(float a, float b) {
    return (unsigned)f2bf(a) | ((unsigned)f2bf(b) << 16);
}

static __device__ __forceinline__ short8v load8(const unsigned short* p) {
    // 8B-aligned: two ds_read_b64
    short4v lo = *(const short4v*)p;
    short4v hi = *(const short4v*)(p + 4);
    return __builtin_shufflevector(lo, hi, 0, 1, 2, 3, 4, 5, 6, 7);
}

__global__ __launch_bounds__(256, 3) void conv3x3_mfma_kernel(
    const float* __restrict__ x,     // [N][C][H][W]
    const float* __restrict__ wgt,   // [OC][C][3][3]
    const float* __restrict__ bias,  // [OC]
    float* __restrict__ out)         // [N][OC][H][W]
{
    __shared__ __align__(16) unsigned short ldsX[3 * XROW];        // 30,960 B
    __shared__ __align__(16) unsigned short ldsW[9 * 32 * WSTRD];  // 20,736 B

    const int tid = threadIdx.x;

    // XCD-aware swizzle: 8 XCDs x 512 consecutive (n,h) rows each.
    const int id = blockIdx.x;
    const int L  = (id & 7) * 512 + (id >> 3);
    const int n  = L >> 8;
    const int h  = L & (H_ - 1);

    // ---- stage weights once: [t9][oc] stride 36, all 32 ic (coalesced) ----
    for (int i = tid; i < OC_ * C_ * 9; i += 256) {
        const float v = wgt[i];
        const int oc  = i / 288;
        const int rem = i - oc * 288;
        const int ic  = rem / 9;
        const int t9  = rem - ic * 9;
        ldsW[(t9 * 32 + oc) * WSTRD + ic] = f2bf(v);
    }

    const int lane = tid & 63;
    const int wv   = tid >> 6;       // wave 0..3
    const int col  = lane & 31;      // A: oc; B/D: w col
    const int qd   = lane >> 5;      // k-quad select

    float16v acc0, acc1;
    #pragma unroll
    for (int r = 0; r < 16; ++r) {
        const float bv = bias[(r & 3) + 8 * (r >> 2) + 4 * qd];
        acc0[r] = bv;
        acc1[r] = bv;
    }

    const int wlo = tid & 31;        // staging: w-pair lane
    const int icp = tid >> 5;        // staging: ic pair within half (0..7)
    const int w0a = wv * 64;
    const int w0b = wv * 64 + 32;

    for (int half = 0; half < 2; ++half) {
        if (half) __syncthreads();   // readers of previous half done

        // ---- stage ldsX for this ic-half: [r][wi] 16 ic packed ----
        const int icg = half * 16 + 2 * icp;
        #pragma unroll
        for (int r = 0; r < 3; ++r) {
            const int hy = h + r - 1;                 // block-uniform branch
            unsigned short* dst = &ldsX[r * XROW];
            if (hy >= 0 && hy < H_) {
                const float* p0 = x + (((size_t)(n * C_ + icg) * H_ + hy) * W_);
                const float* p1 = p0 + (size_t)H_ * W_;
                #pragma unroll
                for (int wb = 0; wb < 4; ++wb) {
                    const int w = wb * 64 + 2 * wlo;
                    const float2 a = *(const float2*)(p0 + w);
                    const float2 b = *(const float2*)(p1 + w);
                    *(unsigned*)&dst[(w + 1) * XSTR + 2 * icp] = pk2(a.x, b.x);
                    *(unsigned*)&dst[(w + 2) * XSTR + 2 * icp] = pk2(a.y, b.y);
                }
            } else {
                #pragma unroll
                for (int wb = 0; wb < 4; ++wb) {
                    const int w = wb * 64 + 2 * wlo;
                    *(unsigned*)&dst[(w + 1) * XSTR + 2 * icp] = 0u;
                    *(unsigned*)&dst[(w + 2) * XSTR + 2 * icp] = 0u;
                }
            }
        }
        // halo columns wi=0 (w=-1) and wi=257 (w=256): zero 32B each row
        if (tid < 24) {
            const int r  = tid >> 3;
            const int q  = tid & 7;
            const int wi = (q & 4) ? 257 : 0;
            const int c  = q & 3;
            *(unsigned long long*)&ldsX[r * XROW + wi * XSTR + c * 4] = 0ull;
        }
        __syncthreads();

        // ---- MFMA: 9 taps x 2 tiles, K=16 per call ----
        #pragma unroll
        for (int kh = 0; kh < 3; ++kh) {
            #pragma unroll
            for (int kw = 0; kw < 3; ++kw) {
                const int t9 = kh * 3 + kw;
                const short8v av =
                    load8(&ldsW[(t9 * 32 + col) * WSTRD + half * 16 + qd * 8]);
                const short8v b0 =
                    load8(&ldsX[kh * XROW + (w0a + col + kw) * XSTR + qd * 8]);
                const short8v b1 =
                    load8(&ldsX[kh * XROW + (w0b + col + kw) * XSTR + qd * 8]);
                acc0 = __builtin_amdgcn_mfma_f32_32x32x16_bf16(av, b0, acc0, 0, 0, 0);
                acc1 = __builtin_amdgcn_mfma_f32_32x32x16_bf16(av, b1, acc1, 0, 0, 0);
            }
        }
    }

    // ---- epilogue: D row = oc, col = w (layout verified in R2) ----
    float* outp = out + (size_t)n * OC_ * H_ * W_ + (size_t)h * W_;
    #pragma unroll
    for (int r = 0; r < 16; ++r) {
        const int oc = (r & 3) + 8 * (r >> 2) + 4 * qd;
        outp[(size_t)oc * H_ * W_ + w0a + col] = acc0[r];
        outp[(size_t)oc * H_ * W_ + w0b + col] = acc1[r];
    }
}

extern "C" void kernel_launch(void* const* d_in, const int* in_sizes, int n_in,
                              void* d_out, int out_size, void* d_ws, size_t ws_size,
                              hipStream_t stream) {
    const float* x    = (const float*)d_in[0];
    const float* wgt  = (const float*)d_in[1];
    const float* bias = (const float*)d_in[2];
    float* out        = (float*)d_out;

    dim3 grid(N_ * H_);   // 4096 blocks: one per (n, h)
    dim3 block(256);
    conv3x3_mfma_kernel<<<grid, block, 0, stream>>>(x, wgt, bias, out);
}